// Round 2
// baseline (579.794 us; speedup 1.0000x reference)
//
#include <hip/hip_runtime.h>
#include <hip/hip_bf16.h>

typedef __hip_bfloat16 bf16;

// dtype-flexible scalar load: bf16 or f32 element i
__device__ __forceinline__ float ldf(const void* p, long i, bool isb) {
    return isb ? __bfloat162float(((const bf16*)p)[i]) : ((const float*)p)[i];
}

// HW fp32 atomic (global_atomic_add_f32, no CAS loop).
__device__ __forceinline__ void atomAdd(float* p, float v) {
    unsafeAtomicAdd(p, v);
}

// Per-tensor input dtype detection.
// flags[0]: x bf16?  flags[1]: edge_attr bf16?  flags[2]: weights bf16?  flags[3]: idx int64?
__global__ void detect_kernel(const unsigned short* __restrict__ x16,
                              const unsigned short* __restrict__ ea16,
                              const unsigned short* __restrict__ we16,
                              const int* __restrict__ ei,
                              unsigned* __restrict__ flags)
{
    __shared__ int cnt[4];
    int t = threadIdx.x; // 256 threads
    if (t < 4) cnt[t] = 0;
    __syncthreads();
    auto sane = [](unsigned short u) { int ex = (u >> 7) & 0xFF; return ex >= 97 && ex <= 157; };
    if (sane(x16[t]))  atomicAdd(&cnt[0], 1);
    if (sane(ea16[t])) atomicAdd(&cnt[1], 1);
    if (t < 32 && sane(we16[t])) atomicAdd(&cnt[2], 1);
    if (t < 32 && ei[2 * t + 1] == 0) atomicAdd(&cnt[3], 1);
    __syncthreads();
    if (t == 0) {
        flags[0] = (cnt[0] >= 240) ? 1u : 0u;
        flags[1] = (cnt[1] >= 240) ? 1u : 0u;
        flags[2] = (cnt[2] >= 29) ? 1u : 0u;
        flags[3] = (cnt[3] == 32) ? 1u : 0u;
    }
}

// Pass A (single edge pass with atomics):
//   pair_pred -> d_out (f32), (ex, dst) -> tail ws,
//   SPLIT-PLANE accumulation: rep[r*2N + d] += ex (denom plane),
//                             rep[r*2N + N + d] += ex*x[src] (numer plane).
// Plane split: the pair of atomics per edge hits two DIFFERENT 32B sectors
// (N*4 bytes apart) -> no same-sector RMW turnaround hazard at the
// memory-side atomic units. Replica r = blockIdx & rmask spreads contention.
__global__ void passA_kernel(const void* __restrict__ x, const int* __restrict__ ei,
                             const void* __restrict__ ea,
                             const void* __restrict__ W_node, const void* __restrict__ W_edge,
                             float2* __restrict__ out_pp, float* __restrict__ tail,
                             float* __restrict__ rep,
                             const unsigned* __restrict__ flags,
                             int E, int N, int rmask, int packed)
{
    __shared__ float wn[4];
    __shared__ float we[32];
    const bool fx = flags[0] != 0, fe = flags[1] != 0;
    const bool fw = flags[2] != 0, i64 = flags[3] != 0;
    {
        int tt = threadIdx.x;
        if (tt < 4)  wn[tt] = ldf(W_node, tt, fw);
        if (tt < 32) we[tt] = ldf(W_edge, tt, fw);
    }
    __syncthreads();

    int e = blockIdx.x * blockDim.x + threadIdx.x;
    if (e >= E) return;

    size_t sw = i64 ? (size_t)2 * e : (size_t)e;
    size_t dw = i64 ? ((size_t)2 * E + 2 * (size_t)e) : ((size_t)E + e);
    int s = ei[sw], d = ei[dw];

    float xs = ldf(x, s, fx), xd = ldf(x, d, fx);
    float l0 = xs * wn[0] + xd * wn[2];
    float l1 = xs * wn[1] + xd * wn[3];

    if (fe) {
        const uint4* p = (const uint4*)((const bf16*)ea + (size_t)e * 16);
        uint4 a = p[0], b = p[1];
        unsigned w[8] = {a.x, a.y, a.z, a.w, b.x, b.y, b.z, b.w};
#pragma unroll
        for (int k = 0; k < 8; ++k) {
            float lo = __uint_as_float(w[k] << 16);
            float hi = __uint_as_float(w[k] & 0xFFFF0000u);
            l0 += lo * we[4 * k + 0] + hi * we[4 * k + 2];
            l1 += lo * we[4 * k + 1] + hi * we[4 * k + 3];
        }
    } else {
        const float4* p = (const float4*)((const float*)ea + (size_t)e * 16);
#pragma unroll
        for (int q = 0; q < 4; ++q) {
            float4 v = p[q];
            l0 += v.x * we[8 * q + 0] + v.y * we[8 * q + 2] +
                  v.z * we[8 * q + 4] + v.w * we[8 * q + 6];
            l1 += v.x * we[8 * q + 1] + v.y * we[8 * q + 3] +
                  v.z * we[8 * q + 5] + v.w * we[8 * q + 7];
        }
    }

    float pp0 = l0 >= 0.f ? l0 : 0.2f * l0;  // leaky_relu(., 0.2)
    float pp1 = l1 >= 0.f ? l1 : 0.2f * l1;
    out_pp[e] = make_float2(pp0, pp1);

    float sc = fminf(pp0 - pp1, 80.f);   // clamp only guards f32 exp overflow
    float ex = expf(sc);

    if (packed) {
        ((float2*)tail)[e] = make_float2(ex, __int_as_float(d)); // passB: no ei re-read
    } else {
        tail[e] = ex;
    }

    float* base = rep + (size_t)((unsigned)blockIdx.x & (unsigned)rmask) * (size_t)2 * N;
    atomAdd(base + d,     ex);        // denom plane
    atomAdd(base + N + d, ex * xs);   // numer plane (different sector/channel)
}

// Reduce replicas -> denom_tot (for passB) and node output directly.
// Split-plane layout makes both read streams stride-1 coalesced.
__global__ void reduce_kernel(const float* __restrict__ rep,
                              float* __restrict__ denom_tot,
                              float* __restrict__ out_node,
                              const void* __restrict__ W,
                              const unsigned* __restrict__ flags,
                              int N, int R)
{
    int n = blockIdx.x * blockDim.x + threadIdx.x;
    if (n >= N) return;
    const bool fw = flags[2] != 0;
    float den = 0.f, num = 0.f;
    for (int r = 0; r < R; ++r) {
        den += rep[(size_t)r * 2 * N + n];
        num += rep[(size_t)r * 2 * N + N + n];
    }
    denom_tot[n] = den;
    float w0 = ldf(W, 0, fw);
    out_node[n] = w0 * num / (den + 1e-16f);
}

// Pass B (atomic-free): attn = ex / (denom_tot[dst] + 1e-16)
__global__ void passB_kernel(const int* __restrict__ ei,
                             const float* __restrict__ tail,
                             const float* __restrict__ denom_tot,
                             float* __restrict__ out_attn,
                             const unsigned* __restrict__ flags, int E, int packed)
{
    int e = blockIdx.x * blockDim.x + threadIdx.x;
    if (e >= E) return;
    if (packed) {
        float2 v = ((const float2*)tail)[e];
        int d = __float_as_int(v.y);
        out_attn[e] = v.x / (denom_tot[d] + 1e-16f);
    } else {
        const bool i64 = flags[3] != 0;
        size_t dw = i64 ? ((size_t)2 * E + 2 * (size_t)e) : ((size_t)E + e);
        int d = ei[dw];
        out_attn[e] = tail[e] / (denom_tot[d] + 1e-16f);
    }
}

extern "C" void kernel_launch(void* const* d_in, const int* in_sizes, int n_in,
                              void* d_out, int out_size, void* d_ws, size_t ws_size,
                              hipStream_t stream)
{
    const void* x      = d_in[0];
    const int*  ei     = (const int*)d_in[1];
    const void* ea     = d_in[2];
    const void* W      = d_in[3];
    const void* W_node = d_in[4];
    const void* W_edge = d_in[5];

    const int N = in_sizes[0];       // x is [N,1]
    const int E = in_sizes[1] / 2;   // edge_index is [2,E]

    // outputs (all f32): out[N] ++ attn[E] ++ pair_pred[2E]
    float*  out_node = (float*)d_out;
    float*  out_attn = out_node + N;
    float2* out_pp   = (float2*)(out_attn + E);

    // ws layout: flags[4] u32 | rep[R*2N] f32 (den plane, num plane per r)
    //            | denom_tot[N] f32 | tail (packed: (ex,dst) float2[E]; else f32[E])
    int R = 1, packed = 0;
    {
        auto fixed = [&](int cand) {
            return (size_t)16 + (size_t)cand * 2 * N * 4 + (size_t)N * 4;
        };
        for (int cand = 16; cand >= 1 && !R; ) { break; } // (no-op, clarity)
        int chosen = 0;
        for (int cand = 16; cand >= 1; cand >>= 1) {
            if (ws_size >= fixed(cand) + (size_t)E * 8) { chosen = cand; packed = 1; break; }
        }
        if (!chosen) {
            for (int cand = 16; cand >= 1; cand >>= 1) {
                if (ws_size >= fixed(cand) + (size_t)E * 4) { chosen = cand; packed = 0; break; }
            }
        }
        R = chosen > 0 ? chosen : 1;
    }
    const int rmask = R - 1;

    unsigned* flags     = (unsigned*)d_ws;
    float*    rep       = (float*)(flags + 4);
    float*    denom_tot = rep + (size_t)R * 2 * N;
    float*    tail      = denom_tot + N;

    hipMemsetAsync(rep, 0, (size_t)R * 2 * N * sizeof(float), stream);

    const int blk = 256;
    const int gE = (E + blk - 1) / blk;
    const int gN = (N + blk - 1) / blk;

    detect_kernel<<<1, 256, 0, stream>>>((const unsigned short*)x,
                                         (const unsigned short*)ea,
                                         (const unsigned short*)W_edge, ei, flags);
    passA_kernel<<<gE, blk, 0, stream>>>(x, ei, ea, W_node, W_edge,
                                         out_pp, tail, rep, flags,
                                         E, N, rmask, packed);
    reduce_kernel<<<gN, blk, 0, stream>>>(rep, denom_tot, out_node, W, flags, N, R);
    passB_kernel<<<gE, blk, 0, stream>>>(ei, tail, denom_tot, out_attn, flags, E, packed);
}